// Round 17
// baseline (158.239 us; speedup 1.0000x reference)
//
#include <hip/hip_runtime.h>

typedef int v4i __attribute__((ext_vector_type(4)));

#define NIMG 32
#define CIN  256
#define COUT 256
#define HW   3136   // 56*56
#define W56  56
#define HP   58     // padded H/W
#define PIMG (HP * HP)                       // 3364
#define WP_BYTES  (9 * COUT * CIN)           // 589,824 (wp2 FIRST in ws)
#define XQP_BYTES (NIMG * PIMG * CIN)        // 27,557,888
#define RHBYTES   (4 * HP * 128)             // 29,696 half-region bytes
#define RHGRAN    (4 * HP * 8)               // 1,856 16B granules per half

#define VMCNT0()  asm volatile("s_waitcnt vmcnt(0)" ::: "memory")

__device__ __forceinline__ void gll16(const void* g, void* l)
{
    __builtin_amdgcn_global_load_lds(
        (const __attribute__((address_space(1))) int*)g,
        (__attribute__((address_space(3))) int*)l, 16, 0, 0);
}

// ---------------------------------------------------------------------------
// Kernel 0: zero only the pad border (228 px/image * 256B)
// ---------------------------------------------------------------------------
__global__ __launch_bounds__(256) void zero_border(v4i* __restrict__ p)
{
    int i = blockIdx.x * 256 + threadIdx.x;
    if (i >= NIMG * 228 * 16) return;
    int n = i / 3648, r = i % 3648, pix = r >> 4, c = r & 15;
    int h, w;
    if (pix < 58)       { h = 0;         w = pix;       }
    else if (pix < 116) { h = 57;        w = pix - 58;  }
    else if (pix < 172) { h = pix - 115; w = 0;         }
    else                { h = pix - 171; w = 57;        }
    v4i z = {0, 0, 0, 0};
    p[(size_t)(n * PIMG + h * HP + w) * 16 + c] = z;
}

// ---------------------------------------------------------------------------
// Kernel 1: quantize + transpose  NCHW f32 -> padded NHWC int8 (interior)
// ---------------------------------------------------------------------------
__global__ __launch_bounds__(256) void quantize_pad(
    const float* __restrict__ x, signed char* __restrict__ xqp)
{
    __shared__ int tile[64][65];
    const int n  = blockIdx.z;
    const int c0 = blockIdx.y * 64;
    const int p0 = blockIdx.x * 64;
    const int tid = threadIdx.x;

    const int px   = tid & 63;
    const int crow = tid >> 6;
    const float* xb = x + ((size_t)(n * CIN + c0)) * HW + p0;
#pragma unroll
    for (int i = 0; i < 16; ++i) {
        int c = crow + i * 4;
        float v = xb[(size_t)c * HW + px];
        v = fminf(fmaxf(v, -1.f), 1.f);
        tile[c][px] = (int)rintf(v * 127.f);
    }
    __syncthreads();

    const int c4   = tid & 15;
    const int prow = tid >> 4;
#pragma unroll
    for (int i = 0; i < 4; ++i) {
        int p  = prow + i * 16;
        int hw = p0 + p;
        int oh = hw / W56, ow = hw % W56;
        int b0 = tile[c4 * 4 + 0][p] & 255;
        int b1 = tile[c4 * 4 + 1][p] & 255;
        int b2 = tile[c4 * 4 + 2][p] & 255;
        int b3 = tile[c4 * 4 + 3][p] & 255;
        int packed = b0 | (b1 << 8) | (b2 << 16) | (b3 << 24);
        *(int*)(xqp + ((size_t)(n * PIMG + (oh + 1) * HP + (ow + 1))) * CIN
                    + c0 + c4 * 4) = packed;
    }
}

// ---------------------------------------------------------------------------
// Kernel 2: weight repack  OIHW int32{-1,0,1} -> [step 0..35][cout 256][64B]
// ---------------------------------------------------------------------------
__global__ __launch_bounds__(256) void repack_w(
    const int* __restrict__ wq, signed char* __restrict__ wp2)
{
    int idx  = blockIdx.x * 256 + threadIdx.x;   // < 589824
    int t    = idx >> 16;
    int rem  = idx & 65535;
    int kc   = rem >> 14;
    int rem2 = rem & 16383;
    int co   = rem2 >> 6;
    int c6   = rem2 & 63;
    int ci   = kc * 64 + c6;
    wp2[idx] = (signed char)wq[(co * CIN + ci) * 9 + t];
}

// ---------------------------------------------------------------------------
// Kernel 3: B-stationary conv, HIGH-OCCUPANCY variant (4 waves/SIMD).
// Block = 128 cout x 112 px (2 out rows), 256 thr = 4 waves of 32c x 112px
// (acc[2][7] = 56 acc regs; total ~110 <= 128 cap via launch_bounds(256,4)).
// Region split into two 128-channel halves (29.7KB LDS) staged sequentially;
// within a half: 18 barrier-free steps, in-step swizzled B ds_read + 1-step
// A reg prefetch (R14-proven). 4 blocks/CU = 16 waves/CU.
// ---------------------------------------------------------------------------
__global__ __launch_bounds__(256, 4) void bitconv_conv(
    const signed char* __restrict__ xqp, const signed char* __restrict__ wp2,
    const float* __restrict__ scale, const float* __restrict__ bias,
    const float* __restrict__ act_s_p, float* __restrict__ out)
{
    __shared__ signed char Bq[RHBYTES];     // persistent half-region

    const int tid  = threadIdx.x;
    const int lane = tid & 63;
    const int wid  = tid >> 6;          // 0..3 -> couts cout0 + wid*32..+31
    const int l15  = lane & 15;
    const int kg   = lane >> 4;

    // XCD swizzle: 1792 = 8*224; adjacent w share the region (L2 pairing)
    const int b     = blockIdx.x;
    const int w     = (b & 7) * 224 + (b >> 3);
    const int cout0 = (w & 1) * 128;
    const int w2    = w >> 1;           // 0..895 row-pair id
    const int n     = w2 / 28;
    const int r0    = (w2 % 28) * 2;    // output row base

    // ---- per-lane B pixel bases (output-px fragment j) ----
    int ppj[7];
#pragma unroll
    for (int j = 0; j < 7; ++j) {
        int opx  = j * 16 + l15;            // 0..111
        int orow = opx / 56, ocol = opx % 56;
        ppj[j] = (orow + 1) * HP + (ocol + 1);
    }

    // ---- A base: per-wave 32 couts, 2 frags ----
    const signed char* ap = wp2 + (cout0 + wid * 32 + l15) * 64 + kg * 16;

    v4i acc[2][7] = {};

    for (int h = 0; h < 2; ++h) {
        if (h) __syncthreads();         // WAR: half-0 reads complete

        // ---- stage half-region (channels h*128..h*128+127) ----
        const signed char* rsrc =
            xqp + ((size_t)n * PIMG + r0 * HP) * 256 + h * 128;
#pragma unroll
        for (int it = 0; it < 8; ++it) {
            int g = it * 256 + tid;
            if (g < RHGRAN) {           // tail: wave 0 only (wave-uniform)
                int pix = g >> 3, ch = g & 7;
                gll16(rsrc + pix * 256 + ((ch ^ (pix & 7)) << 4),
                      Bq + g * 16);
            }
        }
        VMCNT0();
        __syncthreads();

        // ---- 18 barrier-free steps (9 taps x 2 kc-within-half) ----
        const signed char* aps = ap + (2 * h) * 16384;
        v4i aa0 = *(const v4i*)(aps);
        v4i aa1 = *(const v4i*)(aps + 1024);

        for (int t9 = 0; t9 < 9; ++t9) {
            const int pshift = (t9 / 3 - 1) * HP + (t9 % 3 - 1);
            int q[7];
#pragma unroll
            for (int j = 0; j < 7; ++j) {
                int pix = ppj[j] + pshift;
                q[j] = pix * 128 ^ ((pix & 7) << 4) ^ (kg << 4);
            }
#pragma unroll
            for (int kcw = 0; kcw < 2; ++kcw) {
                // prefetch next step's A (overrun past end is harmless)
                const signed char* an = aps + (kcw == 0 ? 16384 : 65536);
                v4i n0 = *(const v4i*)(an);
                v4i n1 = *(const v4i*)(an + 1024);

                __builtin_amdgcn_s_setprio(1);
#pragma unroll
                for (int j = 0; j < 7; ++j) {
                    v4i bb = *(const v4i*)(Bq + (q[j] ^ (kcw << 6)));
                    acc[0][j] = __builtin_amdgcn_mfma_i32_16x16x64_i8(
                        aa0, bb, acc[0][j], 0, 0, 0);
                    acc[1][j] = __builtin_amdgcn_mfma_i32_16x16x64_i8(
                        aa1, bb, acc[1][j], 0, 0, 0);
                }
                __builtin_amdgcn_s_setprio(0);
                aa0 = n0; aa1 = n1;
            }
            aps += 65536;               // next tap, same half
        }
    }

    // ---- epilogue: y = acc * (act_s * scale[c]) + bias[c], NCHW f32 ----
    const float a_s = act_s_p[0];
    const int hw0 = r0 * W56;
#pragma unroll
    for (int i = 0; i < 2; ++i) {
        int cb = cout0 + wid * 32 + i * 16 + kg * 4;
        float sc[4], bi[4];
#pragma unroll
        for (int r = 0; r < 4; ++r) {
            sc[r] = a_s * scale[cb + r];
            bi[r] = bias[cb + r];
        }
#pragma unroll
        for (int j = 0; j < 7; ++j) {
            int px = j * 16 + l15;
#pragma unroll
            for (int r = 0; r < 4; ++r)
                out[((size_t)(n * COUT + cb + r)) * HW + hw0 + px] =
                    (float)acc[i][j][r] * sc[r] + bi[r];
        }
    }
}

// ---------------------------------------------------------------------------
extern "C" void kernel_launch(void* const* d_in, const int* in_sizes, int n_in,
                              void* d_out, int out_size, void* d_ws, size_t ws_size,
                              hipStream_t stream)
{
    const float* x     = (const float*)d_in[0];
    const int*   w_q   = (const int*)d_in[1];
    const float* s     = (const float*)d_in[2];
    const float* bias  = (const float*)d_in[3];
    const float* act_s = (const float*)d_in[4];

    signed char* wp2 = (signed char*)d_ws;                 // weights first
    signed char* xqp = (signed char*)d_ws + WP_BYTES;      // then padded xq

    zero_border<<<(NIMG * 228 * 16 + 255) / 256, 256, 0, stream>>>((v4i*)xqp);
    quantize_pad<<<dim3(49, 4, NIMG), 256, 0, stream>>>(x, xqp);
    repack_w<<<dim3(WP_BYTES / 256), 256, 0, stream>>>(w_q, wp2);
    bitconv_conv<<<dim3(NIMG * 28 * 2), 256, 0, stream>>>(
        xqp, wp2, s, bias, act_s, (float*)d_out);
}

// Round 18
// 93.590 us; speedup vs baseline: 1.6908x; 1.6908x over previous
//
#include <hip/hip_runtime.h>

typedef int v4i __attribute__((ext_vector_type(4)));

#define NIMG 32
#define CIN  256
#define COUT 256
#define HW   3136   // 56*56
#define W56  56
#define HP   58     // padded H/W
#define PIMG (HP * HP)                       // 3364
#define WP_BYTES  (9 * COUT * CIN)           // 589,824 (wp2 FIRST in ws)
#define XQP_BYTES (NIMG * PIMG * CIN)        // 27,557,888
#define RBYTES    (4 * HP * 256)             // 59,392 region bytes
#define NZERO     (NIMG * 228 * 16)          // 116,736 border v4i's

#define VMCNT0()  asm volatile("s_waitcnt vmcnt(0)" ::: "memory")

__device__ __forceinline__ void gll16(const void* g, void* l)
{
    __builtin_amdgcn_global_load_lds(
        (const __attribute__((address_space(1))) int*)g,
        (__attribute__((address_space(3))) int*)l, 16, 0, 0);
}

// ---------------------------------------------------------------------------
// Kernel A: fused aux prep — weight repack + pad-border zeroing
// ---------------------------------------------------------------------------
__global__ __launch_bounds__(256) void aux_prep(
    const int* __restrict__ wq, signed char* __restrict__ wp2,
    v4i* __restrict__ xqp16)
{
    int gid = blockIdx.x * 256 + threadIdx.x;
    if (gid < WP_BYTES) {
        int t    = gid >> 16;
        int rem  = gid & 65535;
        int kc   = rem >> 14;
        int rem2 = rem & 16383;
        int co   = rem2 >> 6;
        int c6   = rem2 & 63;
        int ci   = kc * 64 + c6;
        wp2[gid] = (signed char)wq[(co * CIN + ci) * 9 + t];
    } else {
        int i = gid - WP_BYTES;
        if (i >= NZERO) return;
        int n = i / 3648, r = i % 3648, pix = r >> 4, c = r & 15;
        int h, w;
        if (pix < 58)       { h = 0;         w = pix;       }
        else if (pix < 116) { h = 57;        w = pix - 58;  }
        else if (pix < 172) { h = pix - 115; w = 0;         }
        else                { h = pix - 171; w = 57;        }
        v4i z = {0, 0, 0, 0};
        xqp16[(size_t)(n * PIMG + h * HP + w) * 16 + c] = z;
    }
}

// ---------------------------------------------------------------------------
// Kernel 1: quantize + transpose  NCHW f32 -> padded NHWC int8 (interior)
// ---------------------------------------------------------------------------
__global__ __launch_bounds__(256) void quantize_pad(
    const float* __restrict__ x, signed char* __restrict__ xqp)
{
    __shared__ int tile[64][65];
    const int n  = blockIdx.z;
    const int c0 = blockIdx.y * 64;
    const int p0 = blockIdx.x * 64;
    const int tid = threadIdx.x;

    const int px   = tid & 63;
    const int crow = tid >> 6;
    const float* xb = x + ((size_t)(n * CIN + c0)) * HW + p0;
#pragma unroll
    for (int i = 0; i < 16; ++i) {
        int c = crow + i * 4;
        float v = xb[(size_t)c * HW + px];
        v = fminf(fmaxf(v, -1.f), 1.f);
        tile[c][px] = (int)rintf(v * 127.f);
    }
    __syncthreads();

    const int c4   = tid & 15;
    const int prow = tid >> 4;
#pragma unroll
    for (int i = 0; i < 4; ++i) {
        int p  = prow + i * 16;
        int hw = p0 + p;
        int oh = hw / W56, ow = hw % W56;
        int b0 = tile[c4 * 4 + 0][p] & 255;
        int b1 = tile[c4 * 4 + 1][p] & 255;
        int b2 = tile[c4 * 4 + 2][p] & 255;
        int b3 = tile[c4 * 4 + 3][p] & 255;
        int packed = b0 | (b1 << 8) | (b2 << 16) | (b3 << 24);
        *(int*)(xqp + ((size_t)(n * PIMG + (oh + 1) * HP + (ow + 1))) * CIN
                    + c0 + c4 * 4) = packed;
    }
}

// ---------------------------------------------------------------------------
// Kernel 2: B-stationary conv (R14 structure, micro-tuned).
// Block = 256 cout x 112 px (2 out rows, 1 img), 4 waves of 64c x 112px.
// Region staged once (59KB LDS, swizzled); 36 barrier-free steps:
//   in-step 7 swizzled B ds_read + 4 A global v4i (1-step reg prefetch)
//   -> 28 MFMA. NO setprio (free-running scheduler arbitration).
// Tap-order staggered by per-XCD block parity (taps commute exactly).
// ---------------------------------------------------------------------------
__global__ __launch_bounds__(256, 2) void bitconv_conv(
    const signed char* __restrict__ xqp, const signed char* __restrict__ wp2,
    const float* __restrict__ scale, const float* __restrict__ bias,
    const float* __restrict__ act_s_p, float* __restrict__ out)
{
    __shared__ signed char Bq[RBYTES];      // persistent region, swizzled

    const int tid  = threadIdx.x;
    const int lane = tid & 63;
    const int wid  = tid >> 6;          // 0..3  -> couts wid*64..+63
    const int l15  = lane & 15;
    const int kg   = lane >> 4;

    // XCD swizzle: 896 = 8*112; contiguous tiles per XCD
    const int b  = blockIdx.x;
    const int w  = (b & 7) * 112 + (b >> 3);
    const int n  = w / 28;
    const int r0 = (w % 28) * 2;        // output row base

    // ---- stage region (padded rows r0..r0+3, contiguous in xqp) ----
    {
        const signed char* rsrc = xqp + ((size_t)n * PIMG + r0 * HP) * 256;
        const int base = wid * 64;
#pragma unroll
        for (int it = 0; it < 14; ++it) {
            int g   = it * 256 + base + lane;
            int pix = g >> 4, ch = g & 15;
            int src = pix * 256 + ((ch ^ (pix & 7)) << 4);
            gll16(rsrc + src, Bq + (it * 256 + base) * 16);
        }
        if (wid < 2) {                  // tail: granules 3584..3711
            int g   = 3584 + base + lane;
            int pix = g >> 4, ch = g & 15;
            int src = pix * 256 + ((ch ^ (pix & 7)) << 4);
            gll16(rsrc + src, Bq + (3584 + base) * 16);
        }
        VMCNT0();
        __syncthreads();
    }

    // ---- per-lane B pixel bases (output-px fragment j) ----
    int ppj[7];
#pragma unroll
    for (int j = 0; j < 7; ++j) {
        int opx  = j * 16 + l15;            // 0..111
        int orow = opx / 56, ocol = opx % 56;
        ppj[j] = (orow + 1) * HP + (ocol + 1);
    }

    // ---- A: per-wave 64 couts, 4 frags, direct global w/ 1-step prefetch ---
    const signed char* ap = wp2 + (wid * 64 + l15) * 64 + kg * 16;

    // tap-order stagger: co-resident blocks start 4 taps apart
    const int toff = ((b >> 3) & 1) * 4;

    int t9 = toff;
    const signed char* aps = ap + t9 * 65536;
    v4i aa[2][4];
#pragma unroll
    for (int i = 0; i < 4; ++i) aa[0][i] = *(const v4i*)(aps + i * 1024);

    v4i acc[4][7] = {};

    for (int tt = 0; tt < 9; ++tt) {
        const int t9n = (tt == 8) ? t9 : ((t9 == 8) ? 0 : t9 + 1);
        const signed char* apn = ap + t9n * 65536;

        const int pshift = (t9 / 3 - 1) * HP + (t9 % 3 - 1);
        int q[7];
#pragma unroll
        for (int j = 0; j < 7; ++j) {
            int pix = ppj[j] + pshift;
            q[j] = pix * 256 ^ ((pix & 7) << 4) ^ (kg << 4);
        }
#pragma unroll
        for (int kc = 0; kc < 4; ++kc) {
            const int cu = kc & 1, nx = cu ^ 1;     // static after unroll
            // prefetch A for next step (wraps to next tap at kc==3)
            const signed char* an = (kc < 3) ? aps + (kc + 1) * 16384 : apn;
#pragma unroll
            for (int i = 0; i < 4; ++i)
                aa[nx][i] = *(const v4i*)(an + i * 1024);

#pragma unroll
            for (int j = 0; j < 7; ++j) {
                v4i bb = *(const v4i*)(Bq + (q[j] ^ (kc << 6)));
#pragma unroll
                for (int i = 0; i < 4; ++i)
                    acc[i][j] = __builtin_amdgcn_mfma_i32_16x16x64_i8(
                        aa[cu][i], bb, acc[i][j], 0, 0, 0);
            }
        }
        aps = apn;
        t9  = t9n;
    }

    // ---- epilogue: y = acc * (act_s * scale[c]) + bias[c], NCHW f32 ----
    const float a_s = act_s_p[0];
    const int hw0 = r0 * W56;
#pragma unroll
    for (int i = 0; i < 4; ++i) {
        int cb = wid * 64 + i * 16 + kg * 4;
        float sc[4], bi[4];
#pragma unroll
        for (int r = 0; r < 4; ++r) {
            sc[r] = a_s * scale[cb + r];
            bi[r] = bias[cb + r];
        }
#pragma unroll
        for (int j = 0; j < 7; ++j) {
            int px = j * 16 + l15;
#pragma unroll
            for (int r = 0; r < 4; ++r)
                out[((size_t)(n * COUT + cb + r)) * HW + hw0 + px] =
                    (float)acc[i][j][r] * sc[r] + bi[r];
        }
    }
}

// ---------------------------------------------------------------------------
extern "C" void kernel_launch(void* const* d_in, const int* in_sizes, int n_in,
                              void* d_out, int out_size, void* d_ws, size_t ws_size,
                              hipStream_t stream)
{
    const float* x     = (const float*)d_in[0];
    const int*   w_q   = (const int*)d_in[1];
    const float* s     = (const float*)d_in[2];
    const float* bias  = (const float*)d_in[3];
    const float* act_s = (const float*)d_in[4];

    signed char* wp2 = (signed char*)d_ws;                 // weights first
    signed char* xqp = (signed char*)d_ws + WP_BYTES;      // then padded xq

    aux_prep<<<dim3((WP_BYTES + NZERO + 255) / 256), 256, 0, stream>>>(
        w_q, wp2, (v4i*)xqp);
    quantize_pad<<<dim3(49, 4, NIMG), 256, 0, stream>>>(x, xqp);
    bitconv_conv<<<dim3(NIMG * 28), 256, 0, stream>>>(
        xqp, wp2, s, bias, act_s, (float*)d_out);
}

// Round 19
// 82.986 us; speedup vs baseline: 1.9068x; 1.1278x over previous
//
#include <hip/hip_runtime.h>

typedef int v4i __attribute__((ext_vector_type(4)));

#define NIMG 32
#define CIN  256
#define COUT 256
#define HW   3136   // 56*56
#define W56  56
#define HP   58     // padded H/W
#define PIMG (HP * HP)                       // 3364
#define WP_BYTES  (9 * COUT * CIN)           // 589,824 (wp2 FIRST in ws)
#define XQP_BYTES (NIMG * PIMG * CIN)        // 27,557,888
#define RBYTES    (4 * HP * 256)             // 59,392 region bytes
#define NZERO     (NIMG * 228 * 16)          // 116,736 border v4i's

#define VMCNT0()  asm volatile("s_waitcnt vmcnt(0)" ::: "memory")

__device__ __forceinline__ void gll16(const void* g, void* l)
{
    __builtin_amdgcn_global_load_lds(
        (const __attribute__((address_space(1))) int*)g,
        (__attribute__((address_space(3))) int*)l, 16, 0, 0);
}

// ---------------------------------------------------------------------------
// Kernel A: fused aux prep — weight repack + pad-border zeroing
// ---------------------------------------------------------------------------
__global__ __launch_bounds__(256) void aux_prep(
    const int* __restrict__ wq, signed char* __restrict__ wp2,
    v4i* __restrict__ xqp16)
{
    int gid = blockIdx.x * 256 + threadIdx.x;
    if (gid < WP_BYTES) {
        int t    = gid >> 16;
        int rem  = gid & 65535;
        int kc   = rem >> 14;
        int rem2 = rem & 16383;
        int co   = rem2 >> 6;
        int c6   = rem2 & 63;
        int ci   = kc * 64 + c6;
        wp2[gid] = (signed char)wq[(co * CIN + ci) * 9 + t];
    } else {
        int i = gid - WP_BYTES;
        if (i >= NZERO) return;
        int n = i / 3648, r = i % 3648, pix = r >> 4, c = r & 15;
        int h, w;
        if (pix < 58)       { h = 0;         w = pix;       }
        else if (pix < 116) { h = 57;        w = pix - 58;  }
        else if (pix < 172) { h = pix - 115; w = 0;         }
        else                { h = pix - 171; w = 57;        }
        v4i z = {0, 0, 0, 0};
        xqp16[(size_t)(n * PIMG + h * HP + w) * 16 + c] = z;
    }
}

// ---------------------------------------------------------------------------
// Kernel 1: quantize + transpose  NCHW f32 -> padded NHWC int8 (interior)
// ---------------------------------------------------------------------------
__global__ __launch_bounds__(256) void quantize_pad(
    const float* __restrict__ x, signed char* __restrict__ xqp)
{
    __shared__ int tile[64][65];
    const int n  = blockIdx.z;
    const int c0 = blockIdx.y * 64;
    const int p0 = blockIdx.x * 64;
    const int tid = threadIdx.x;

    const int px   = tid & 63;
    const int crow = tid >> 6;
    const float* xb = x + ((size_t)(n * CIN + c0)) * HW + p0;
#pragma unroll
    for (int i = 0; i < 16; ++i) {
        int c = crow + i * 4;
        float v = xb[(size_t)c * HW + px];
        v = fminf(fmaxf(v, -1.f), 1.f);
        tile[c][px] = (int)rintf(v * 127.f);
    }
    __syncthreads();

    const int c4   = tid & 15;
    const int prow = tid >> 4;
#pragma unroll
    for (int i = 0; i < 4; ++i) {
        int p  = prow + i * 16;
        int hw = p0 + p;
        int oh = hw / W56, ow = hw % W56;
        int b0 = tile[c4 * 4 + 0][p] & 255;
        int b1 = tile[c4 * 4 + 1][p] & 255;
        int b2 = tile[c4 * 4 + 2][p] & 255;
        int b3 = tile[c4 * 4 + 3][p] & 255;
        int packed = b0 | (b1 << 8) | (b2 << 16) | (b3 << 24);
        *(int*)(xqp + ((size_t)(n * PIMG + (oh + 1) * HP + (ow + 1))) * CIN
                    + c0 + c4 * 4) = packed;
    }
}

// ---------------------------------------------------------------------------
// Kernel 2: B-stationary conv (R14-proven structure, verbatim).
// Block = 256 cout x 112 px (2 out rows, 1 img), 4 waves of 64c x 112px.
// Region staged once (59KB LDS, swizzled); 36 barrier-free steps:
//   in-step 7 swizzled B ds_read + 4 A global v4i (1-step reg prefetch,
//   L2-resident weights) -> 28 MFMA with setprio around the cluster.
// ---------------------------------------------------------------------------
__global__ __launch_bounds__(256, 2) void bitconv_conv(
    const signed char* __restrict__ xqp, const signed char* __restrict__ wp2,
    const float* __restrict__ scale, const float* __restrict__ bias,
    const float* __restrict__ act_s_p, float* __restrict__ out)
{
    __shared__ signed char Bq[RBYTES];      // persistent region, swizzled

    const int tid  = threadIdx.x;
    const int lane = tid & 63;
    const int wid  = tid >> 6;          // 0..3  -> couts wid*64..+63
    const int l15  = lane & 15;
    const int kg   = lane >> 4;

    // XCD swizzle: 896 = 8*112; contiguous tiles per XCD
    const int b  = blockIdx.x;
    const int w  = (b & 7) * 112 + (b >> 3);
    const int n  = w / 28;
    const int r0 = (w % 28) * 2;        // output row base

    // ---- stage region (padded rows r0..r0+3, contiguous in xqp) ----
    {
        const signed char* rsrc = xqp + ((size_t)n * PIMG + r0 * HP) * 256;
        const int base = wid * 64;
#pragma unroll
        for (int it = 0; it < 14; ++it) {
            int g   = it * 256 + base + lane;
            int pix = g >> 4, ch = g & 15;
            int src = pix * 256 + ((ch ^ (pix & 7)) << 4);
            gll16(rsrc + src, Bq + (it * 256 + base) * 16);
        }
        if (wid < 2) {                  // tail: granules 3584..3711
            int g   = 3584 + base + lane;
            int pix = g >> 4, ch = g & 15;
            int src = pix * 256 + ((ch ^ (pix & 7)) << 4);
            gll16(rsrc + src, Bq + (3584 + base) * 16);
        }
        VMCNT0();
        __syncthreads();
    }

    // ---- per-lane B pixel bases (output-px fragment j) ----
    int ppj[7];
#pragma unroll
    for (int j = 0; j < 7; ++j) {
        int opx  = j * 16 + l15;            // 0..111
        int orow = opx / 56, ocol = opx % 56;
        ppj[j] = (orow + 1) * HP + (ocol + 1);
    }

    // ---- A: per-wave 64 couts, 4 frags, direct global w/ 1-step prefetch ---
    const signed char* ap = wp2 + (wid * 64 + l15) * 64 + kg * 16;
    v4i aa[2][4];
#pragma unroll
    for (int i = 0; i < 4; ++i) aa[0][i] = *(const v4i*)(ap + i * 1024);

    v4i acc[4][7] = {};
    const signed char* aps = ap;

    for (int t9 = 0; t9 < 9; ++t9) {
        const int pshift = (t9 / 3 - 1) * HP + (t9 % 3 - 1);
        int q[7];
#pragma unroll
        for (int j = 0; j < 7; ++j) {
            int pix = ppj[j] + pshift;
            q[j] = pix * 256 ^ ((pix & 7) << 4) ^ (kg << 4);
        }
#pragma unroll
        for (int kc = 0; kc < 4; ++kc) {
            const int cu = kc & 1, nx = cu ^ 1;     // static after unroll
            // prefetch A for next step (safe overrun into xqp at step 36)
            const signed char* an = aps + 16384;
#pragma unroll
            for (int i = 0; i < 4; ++i)
                aa[nx][i] = *(const v4i*)(an + i * 1024);

            __builtin_amdgcn_s_setprio(1);
#pragma unroll
            for (int j = 0; j < 7; ++j) {
                v4i bb = *(const v4i*)(Bq + (q[j] ^ (kc << 6)));
#pragma unroll
                for (int i = 0; i < 4; ++i)
                    acc[i][j] = __builtin_amdgcn_mfma_i32_16x16x64_i8(
                        aa[cu][i], bb, acc[i][j], 0, 0, 0);
            }
            __builtin_amdgcn_s_setprio(0);
            aps = an;
        }
    }

    // ---- epilogue: y = acc * (act_s * scale[c]) + bias[c], NCHW f32 ----
    const float a_s = act_s_p[0];
    const int hw0 = r0 * W56;
#pragma unroll
    for (int i = 0; i < 4; ++i) {
        int cb = wid * 64 + i * 16 + kg * 4;
        float sc[4], bi[4];
#pragma unroll
        for (int r = 0; r < 4; ++r) {
            sc[r] = a_s * scale[cb + r];
            bi[r] = bias[cb + r];
        }
#pragma unroll
        for (int j = 0; j < 7; ++j) {
            int px = j * 16 + l15;
#pragma unroll
            for (int r = 0; r < 4; ++r)
                out[((size_t)(n * COUT + cb + r)) * HW + hw0 + px] =
                    (float)acc[i][j][r] * sc[r] + bi[r];
        }
    }
}

// ---------------------------------------------------------------------------
extern "C" void kernel_launch(void* const* d_in, const int* in_sizes, int n_in,
                              void* d_out, int out_size, void* d_ws, size_t ws_size,
                              hipStream_t stream)
{
    const float* x     = (const float*)d_in[0];
    const int*   w_q   = (const int*)d_in[1];
    const float* s     = (const float*)d_in[2];
    const float* bias  = (const float*)d_in[3];
    const float* act_s = (const float*)d_in[4];

    signed char* wp2 = (signed char*)d_ws;                 // weights first
    signed char* xqp = (signed char*)d_ws + WP_BYTES;      // then padded xq

    aux_prep<<<dim3((WP_BYTES + NZERO + 255) / 256), 256, 0, stream>>>(
        w_q, wp2, (v4i*)xqp);
    quantize_pad<<<dim3(49, 4, NIMG), 256, 0, stream>>>(x, xqp);
    bitconv_conv<<<dim3(NIMG * 28), 256, 0, stream>>>(
        xqp, wp2, s, bias, act_s, (float*)d_out);
}